// Round 1
// 104.733 us; speedup vs baseline: 1.0546x; 1.0546x over previous
//
#include <hip/hip_runtime.h>
#include <math.h>

// Problem constants
#define BSZ   512
#define XD    768
#define YD    128
#define H2D   512

// ---------------------------------------------------------------------------
// layer1: partials of x @ W1 (both branches, split-K x4). NO bias/relu here —
// applied during layer2's A-staging.
//   x:(512,768), W1:(768,512). p1[branch*4+ks][512][512], K-chunk 192.
// Tile 64x64, 4x4 per thread (2 FMA per LDS float), K-tile 16.
// Grid (8,8,9): z<8 = GEMM (branch=z>>2, ks=z&3) -> 512 blocks, 2/CU
//               (split-K x4 doubles occupancy vs x2: 2 waves/SIMD so barrier
//                and LDS stalls of one block overlap the other's FMAs).
//               z==8 = ysum plane: 16 working blocks compute Sy/Sy2 columns
//               of y and zero the fp64 accumulator slots + finalize counter.
// Software prefetch: next tile's global loads issue before the FMA block.
// LDS: As[k][m] stride 68 (transposed scatter, 2-way = free),
//      Bs[k][n] stride 68 (direct float4 store, structural-peak 8 cyc).
// ---------------------------------------------------------------------------
__global__ __launch_bounds__(256, 2) void layer1_kernel(
    const float* __restrict__ x,
    const float* __restrict__ w1_mu, const float* __restrict__ w1_lv,
    const float* __restrict__ y,
    float* __restrict__ p1,
    double* __restrict__ Sy, double* __restrict__ Sy2,
    double* __restrict__ accum, unsigned int* __restrict__ counter)
{
    __shared__ float As[16][68];
    __shared__ float Bs[16][68];
    const int t = threadIdx.x;

    if (blockIdx.z == 8) {
        // ----- ysum plane: Sy[d], Sy2[d] + accumulator init -----
        const int id = blockIdx.x + 8 * blockIdx.y;
        if (id >= 16) return;
        const int dl = t & 7;
        const int g  = t >> 3;                  // 32 row-groups of 16
        const int d  = id * 8 + dl;
        float s = 0.f, s2 = 0.f;
        for (int i = g * 16; i < g * 16 + 16; ++i) {
            const float v = y[i * YD + d];
            s += v; s2 += v * v;
        }
        float* shs  = &As[0][0];                // reuse GEMM LDS
        float* shs2 = &Bs[0][0];
        shs[t] = s; shs2[t] = s2;
        __syncthreads();
        if (t < 8) {
            double S = 0.0, S2 = 0.0;
            #pragma unroll
            for (int gg = 0; gg < 32; ++gg) {
                S += (double)shs[gg * 8 + t]; S2 += (double)shs2[gg * 8 + t];
            }
            Sy[id * 8 + t] = S; Sy2[id * 8 + t] = S2;
        } else if (id == 0 && t >= 8 && t < 40) { accum[t - 8] = 0.0; }
        else if (id == 0 && t == 40)            { *counter = 0u; }
        return;
    }

    // ----- GEMM planes -----
    const int bz     = blockIdx.z;              // 0..7
    const int branch = bz >> 2;
    const int ks     = bz & 3;
    const float* __restrict__ W = branch ? w1_lv : w1_mu;
    float* __restrict__ out = p1 + (size_t)bz * (BSZ * H2D);

    const int m0 = blockIdx.x * 64;
    const int n0 = blockIdx.y * 64;
    const int tx = t & 15;
    const int ty = t >> 4;

    // staging maps: A 64m x 16k (1 float4/thread), B 16k x 64n (1 float4/thread)
    const int am  = t >> 2;                     // 0..63
    const int akq = (t & 3) << 2;               // 0,4,8,12
    const int bkk = t >> 4;                     // 0..15
    const int bnq = (t & 15) << 2;              // 0..60

    const int kbase = ks * 192;
    float acc[4][4] = {};

    float4 a_pref = *(const float4*)&x[(m0 + am) * XD + kbase + akq];
    float4 b_pref = *(const float4*)&W[(kbase + bkk) * H2D + n0 + bnq];

    for (int kt = 0; kt < 192; kt += 16) {
        __syncthreads();                        // LDS readers of prev tile done
        As[akq + 0][am] = a_pref.x;
        As[akq + 1][am] = a_pref.y;
        As[akq + 2][am] = a_pref.z;
        As[akq + 3][am] = a_pref.w;
        *(float4*)&Bs[bkk][bnq] = b_pref;
        __syncthreads();
        if (kt + 16 < 192) {                    // prefetch next tile (hides
            const int kn = kbase + kt + 16;     //  global latency under FMAs)
            a_pref = *(const float4*)&x[(m0 + am) * XD + kn + akq];
            b_pref = *(const float4*)&W[(kn + bkk) * H2D + n0 + bnq];
        }
        #pragma unroll
        for (int k = 0; k < 16; ++k) {
            const float4 av = *(const float4*)&As[k][ty * 4];
            const float4 bv = *(const float4*)&Bs[k][tx * 4];
            acc[0][0] += av.x*bv.x; acc[0][1] += av.x*bv.y; acc[0][2] += av.x*bv.z; acc[0][3] += av.x*bv.w;
            acc[1][0] += av.y*bv.x; acc[1][1] += av.y*bv.y; acc[1][2] += av.y*bv.z; acc[1][3] += av.y*bv.w;
            acc[2][0] += av.z*bv.x; acc[2][1] += av.z*bv.y; acc[2][2] += av.z*bv.z; acc[2][3] += av.z*bv.w;
            acc[3][0] += av.w*bv.x; acc[3][1] += av.w*bv.y; acc[3][2] += av.w*bv.z; acc[3][3] += av.w*bv.w;
        }
    }

    #pragma unroll
    for (int i = 0; i < 4; ++i) {
        const float4 o = make_float4(acc[i][0], acc[i][1], acc[i][2], acc[i][3]);
        *(float4*)&out[(m0 + ty * 4 + i) * H2D + n0 + tx * 4] = o;
    }
}

// ---------------------------------------------------------------------------
// layer2: partials of relu(p1a+p1b+p1c+p1d+b1) @ W2, split-K x8, both branches.
// H recomputed on the fly during A-staging (adds bias, relu). No b2/tanh here.
// H:(512,512), W2:(512,128). Grid (8,2,16): z = branch*8 + ks, K-chunk 64.
// p2[z][512][128]. Same tile template as layer1.
// ---------------------------------------------------------------------------
__global__ __launch_bounds__(256, 2) void layer2_kernel(
    const float* __restrict__ p1,
    const float* __restrict__ b1_mu, const float* __restrict__ b1_lv,
    const float* __restrict__ w2_mu, const float* __restrict__ w2_lv,
    float* __restrict__ p2)
{
    __shared__ float As[16][68];
    __shared__ float Bs[16][68];
    const int t = threadIdx.x;

    const int branch = blockIdx.z >> 3;
    const int ks     = blockIdx.z & 7;
    const float* __restrict__ pa = p1 + (size_t)(branch * 4 + 0) * (BSZ * H2D);
    const float* __restrict__ pb = p1 + (size_t)(branch * 4 + 1) * (BSZ * H2D);
    const float* __restrict__ pc = p1 + (size_t)(branch * 4 + 2) * (BSZ * H2D);
    const float* __restrict__ pd = p1 + (size_t)(branch * 4 + 3) * (BSZ * H2D);
    const float* __restrict__ b1 = branch ? b1_lv : b1_mu;
    const float* __restrict__ W  = branch ? w2_lv : w2_mu;
    float* __restrict__ out = p2 + (size_t)blockIdx.z * (BSZ * YD);

    const int m0 = blockIdx.x * 64;
    const int n0 = blockIdx.y * 64;
    const int tx = t & 15;
    const int ty = t >> 4;

    const int am  = t >> 2;
    const int akq = (t & 3) << 2;
    const int bkk = t >> 4;
    const int bnq = (t & 15) << 2;

    const int kbase = ks * 64;
    float acc[4][4] = {};

    float4 pa4 = *(const float4*)&pa[(m0 + am) * H2D + kbase + akq];
    float4 pb4 = *(const float4*)&pb[(m0 + am) * H2D + kbase + akq];
    float4 pc4 = *(const float4*)&pc[(m0 + am) * H2D + kbase + akq];
    float4 pd4 = *(const float4*)&pd[(m0 + am) * H2D + kbase + akq];
    float4 bb4 = *(const float4*)&b1[kbase + akq];
    float4 w4  = *(const float4*)&W[(kbase + bkk) * YD + n0 + bnq];

    for (int kt = 0; kt < 64; kt += 16) {
        __syncthreads();
        As[akq + 0][am] = fmaxf(pa4.x + pb4.x + pc4.x + pd4.x + bb4.x, 0.f);
        As[akq + 1][am] = fmaxf(pa4.y + pb4.y + pc4.y + pd4.y + bb4.y, 0.f);
        As[akq + 2][am] = fmaxf(pa4.z + pb4.z + pc4.z + pd4.z + bb4.z, 0.f);
        As[akq + 3][am] = fmaxf(pa4.w + pb4.w + pc4.w + pd4.w + bb4.w, 0.f);
        *(float4*)&Bs[bkk][bnq] = w4;
        __syncthreads();
        if (kt + 16 < 64) {
            const int kn = kbase + kt + 16;
            pa4 = *(const float4*)&pa[(m0 + am) * H2D + kn + akq];
            pb4 = *(const float4*)&pb[(m0 + am) * H2D + kn + akq];
            pc4 = *(const float4*)&pc[(m0 + am) * H2D + kn + akq];
            pd4 = *(const float4*)&pd[(m0 + am) * H2D + kn + akq];
            bb4 = *(const float4*)&b1[kn + akq];
            w4  = *(const float4*)&W[(kn + bkk) * YD + n0 + bnq];
        }
        #pragma unroll
        for (int k = 0; k < 16; ++k) {
            const float4 av = *(const float4*)&As[k][ty * 4];
            const float4 bv = *(const float4*)&Bs[k][tx * 4];
            acc[0][0] += av.x*bv.x; acc[0][1] += av.x*bv.y; acc[0][2] += av.x*bv.z; acc[0][3] += av.x*bv.w;
            acc[1][0] += av.y*bv.x; acc[1][1] += av.y*bv.y; acc[1][2] += av.y*bv.z; acc[1][3] += av.y*bv.w;
            acc[2][0] += av.z*bv.x; acc[2][1] += av.z*bv.y; acc[2][2] += av.z*bv.z; acc[2][3] += av.z*bv.w;
            acc[3][0] += av.w*bv.x; acc[3][1] += av.w*bv.y; acc[3][2] += av.w*bv.z; acc[3][3] += av.w*bv.w;
        }
    }

    #pragma unroll
    for (int i = 0; i < 4; ++i) {
        const float4 o = make_float4(acc[i][0], acc[i][1], acc[i][2], acc[i][3]);
        *(float4*)&out[(m0 + ty * 4 + i) * YD + n0 + tx * 4] = o;
    }
}

// ---------------------------------------------------------------------------
// reduce (+inline finalize): per element e=(i,d):
//   mu = sum_s p2[s][e] + b2_mu[d];  lv = tanh(sum_s p2[8+s][e] + b2_lv[d])
//   iv = exp(-lv)
//   pos += -0.5*(mu-y)^2*iv - 0.5*lv
//   ap  += iv*(-0.5*Sy2[d] + mu*Sy[d] - 256*mu^2) - 256*lv
// fp32 elementwise, fp64 block reduction + device atomics spread over 16
// accumulator slots (blockIdx&15) to kill the same-address RMW serialization
// tail (was 512 serialized fp64 atomics on 2 addresses). The LAST block
// (atomic counter) reads the 32 slots back in parallel (32 threads) and
// writes the scalar output.
// ---------------------------------------------------------------------------
__global__ __launch_bounds__(256) void reduce_kernel(
    const float* __restrict__ p2, const float* __restrict__ y,
    const float* __restrict__ b2_mu, const float* __restrict__ b2_lv,
    const double* __restrict__ Sy, const double* __restrict__ Sy2,
    double* __restrict__ accum, unsigned int* __restrict__ counter,
    float* __restrict__ outp)
{
    const int NE = BSZ * YD;
    const int e  = blockIdx.x * 256 + threadIdx.x;   // grid 256 covers exactly
    const int d  = e & (YD - 1);

    float mu = b2_mu[d];
    float lp = b2_lv[d];
    #pragma unroll
    for (int s = 0; s < 8; ++s) {
        mu += p2[s * NE + e];
        lp += p2[(8 + s) * NE + e];
    }
    const float lv = tanhf(lp);
    const float iv = expf(-lv);
    const float dm = mu - y[e];

    double pos = -0.5 * (double)dm * (double)dm * (double)iv - 0.5 * (double)lv;
    double ap  = (double)iv * (-0.5 * Sy2[d] + (double)mu * Sy[d]
                               - 256.0 * (double)mu * (double)mu)
               - 256.0 * (double)lv;

    #pragma unroll
    for (int off = 32; off > 0; off >>= 1) {
        pos += __shfl_down(pos, off);
        ap  += __shfl_down(ap, off);
    }
    __shared__ double sp[4];
    __shared__ double sa[4];
    __shared__ double fin[32];
    __shared__ int lastflag;
    const int lane = threadIdx.x & 63;
    const int wv   = threadIdx.x >> 6;
    if (lane == 0) { sp[wv] = pos; sa[wv] = ap; }
    __syncthreads();
    if (threadIdx.x == 0) {
        const int slot = blockIdx.x & 15;
        atomicAdd(&accum[slot],      sp[0] + sp[1] + sp[2] + sp[3]);
        atomicAdd(&accum[16 + slot], sa[0] + sa[1] + sa[2] + sa[3]);
        __threadfence();
        lastflag = (atomicAdd(counter, 1u) == 255u) ? 1 : 0;
    }
    __syncthreads();
    if (lastflag) {                            // last block: finalize
        if (threadIdx.x < 32)                  // coherent parallel read-back
            fin[threadIdx.x] = atomicAdd(&accum[threadIdx.x], 0.0);
        __syncthreads();
        if (threadIdx.x == 0) {
            double P = 0.0, A = 0.0;
            #pragma unroll
            for (int s = 0; s < 16; ++s) { P += fin[s]; A += fin[16 + s]; }
            const double C = log1p(exp(-20.0) / 511.0);
            outp[0] = (float)(P / 512.0 - A / 262144.0 - C);
        }
    }
}

extern "C" void kernel_launch(void* const* d_in, const int* in_sizes, int n_in,
                              void* d_out, int out_size, void* d_ws, size_t ws_size,
                              hipStream_t stream) {
    const float* x     = (const float*)d_in[0];
    const float* y     = (const float*)d_in[1];
    const float* w1_mu = (const float*)d_in[2];
    const float* b1_mu = (const float*)d_in[3];
    const float* w2_mu = (const float*)d_in[4];
    const float* b2_mu = (const float*)d_in[5];
    const float* w1_lv = (const float*)d_in[6];
    const float* b1_lv = (const float*)d_in[7];
    const float* w2_lv = (const float*)d_in[8];
    const float* b2_lv = (const float*)d_in[9];

    char* ws = (char*)d_ws;
    float*  p1 = (float*)(ws);                                     // 8 MB
    float*  p2 = (float*)(ws + (size_t)8 * BSZ * H2D * 4);         // 4 MB
    double* Sy = (double*)(ws + (size_t)8 * BSZ * H2D * 4
                              + (size_t)16 * BSZ * YD * 4);        // 1 KB
    double* Sy2 = Sy + YD;                                         // 1 KB
    double* accum = Sy2 + YD;                                      // 256 B
    unsigned int* counter = (unsigned int*)(accum + 32);           // 4 B

    layer1_kernel<<<dim3(8, 8, 9), 256, 0, stream>>>(
        x, w1_mu, w1_lv, y, p1, Sy, Sy2, accum, counter);
    layer2_kernel<<<dim3(8, 2, 16), 256, 0, stream>>>(
        p1, b1_mu, b1_lv, w2_mu, w2_lv, p2);
    reduce_kernel<<<256, 256, 0, stream>>>(
        p2, y, b2_mu, b2_lv, Sy, Sy2, accum, counter, (float*)d_out);
}

// Round 2
// 103.952 us; speedup vs baseline: 1.0626x; 1.0075x over previous
//
#include <hip/hip_runtime.h>
#include <math.h>

// Problem constants
#define BSZ   512
#define XD    768
#define YD    128
#define H2D   512

// ---------------------------------------------------------------------------
// layer1: partials of x @ W1 (both branches, split-K x4). NO bias/relu here —
// applied during layer2's A-staging.
//   x:(512,768), W1:(768,512). p1[branch*4+ks][512][512], K-chunk 192.
// Tile 64x64, 4x4 per thread (2 FMA per LDS float), K-tile 16.
// Grid (8,8,9): z<8 = GEMM (branch=z>>2, ks=z&3) -> 512 blocks, 2/CU
//               z==8 = ysum plane (16 working blocks) + accumulator init.
// DOUBLE-BUFFERED LDS: one __syncthreads per K-tile (was 2). Global prefetch
// for tile t+1 issues at the top of the iteration so HBM latency hides under
// the 32-FMA burst. LDS 2x(16x68)x2 arrays = 17.4 KB, still 2 blocks/CU.
// As[k][m] stride 68 (transposed scatter, 2-way = free), Bs[k][n] direct f4.
// ---------------------------------------------------------------------------
__global__ __launch_bounds__(256, 2) void layer1_kernel(
    const float* __restrict__ x,
    const float* __restrict__ w1_mu, const float* __restrict__ w1_lv,
    const float* __restrict__ y,
    float* __restrict__ p1,
    double* __restrict__ Sy, double* __restrict__ Sy2,
    double* __restrict__ accum, unsigned int* __restrict__ counter)
{
    __shared__ float As[2][16][68];
    __shared__ float Bs[2][16][68];
    const int t = threadIdx.x;

    if (blockIdx.z == 8) {
        // ----- ysum plane: Sy[d], Sy2[d] + accumulator init -----
        const int id = blockIdx.x + 8 * blockIdx.y;
        if (id >= 16) return;
        const int dl = t & 7;
        const int g  = t >> 3;                  // 32 row-groups of 16
        const int d  = id * 8 + dl;
        float s = 0.f, s2 = 0.f;
        for (int i = g * 16; i < g * 16 + 16; ++i) {
            const float v = y[i * YD + d];
            s += v; s2 += v * v;
        }
        float* shs  = &As[0][0][0];             // reuse GEMM LDS
        float* shs2 = &Bs[0][0][0];
        shs[t] = s; shs2[t] = s2;
        __syncthreads();
        if (t < 8) {
            double S = 0.0, S2 = 0.0;
            #pragma unroll
            for (int gg = 0; gg < 32; ++gg) {
                S += (double)shs[gg * 8 + t]; S2 += (double)shs2[gg * 8 + t];
            }
            Sy[id * 8 + t] = S; Sy2[id * 8 + t] = S2;
        } else if (id == 0 && t >= 8 && t < 40) { accum[t - 8] = 0.0; }
        else if (id == 0 && t == 40)            { *counter = 0u; }
        return;
    }

    // ----- GEMM planes -----
    const int bz     = blockIdx.z;              // 0..7
    const int branch = bz >> 2;
    const int ks     = bz & 3;
    const float* __restrict__ W = branch ? w1_lv : w1_mu;
    float* __restrict__ out = p1 + (size_t)bz * (BSZ * H2D);

    const int m0 = blockIdx.x * 64;
    const int n0 = blockIdx.y * 64;
    const int tx = t & 15;
    const int ty = t >> 4;

    // staging maps: A 64m x 16k (1 float4/thread), B 16k x 64n (1 float4/thread)
    const int am  = t >> 2;                     // 0..63
    const int akq = (t & 3) << 2;               // 0,4,8,12
    const int bkk = t >> 4;                     // 0..15
    const int bnq = (t & 15) << 2;              // 0..60

    const int kbase = ks * 192;
    float acc[4][4] = {};

    // stage tile 0 into buffer 0
    float4 a_pref = *(const float4*)&x[(m0 + am) * XD + kbase + akq];
    float4 b_pref = *(const float4*)&W[(kbase + bkk) * H2D + n0 + bnq];
    As[0][akq + 0][am] = a_pref.x;
    As[0][akq + 1][am] = a_pref.y;
    As[0][akq + 2][am] = a_pref.z;
    As[0][akq + 3][am] = a_pref.w;
    *(float4*)&Bs[0][bkk][bnq] = b_pref;
    __syncthreads();

    int buf = 0;
    for (int kt = 0; kt < 192; kt += 16) {
        const bool more = (kt + 16 < 192);
        if (more) {                             // issue next tile's loads FIRST
            const int kn = kbase + kt + 16;     //  (hides HBM latency under FMAs)
            a_pref = *(const float4*)&x[(m0 + am) * XD + kn + akq];
            b_pref = *(const float4*)&W[(kn + bkk) * H2D + n0 + bnq];
        }
        #pragma unroll
        for (int k = 0; k < 16; ++k) {
            const float4 av = *(const float4*)&As[buf][k][ty * 4];
            const float4 bv = *(const float4*)&Bs[buf][k][tx * 4];
            acc[0][0] += av.x*bv.x; acc[0][1] += av.x*bv.y; acc[0][2] += av.x*bv.z; acc[0][3] += av.x*bv.w;
            acc[1][0] += av.y*bv.x; acc[1][1] += av.y*bv.y; acc[1][2] += av.y*bv.z; acc[1][3] += av.y*bv.w;
            acc[2][0] += av.z*bv.x; acc[2][1] += av.z*bv.y; acc[2][2] += av.z*bv.z; acc[2][3] += av.z*bv.w;
            acc[3][0] += av.w*bv.x; acc[3][1] += av.w*bv.y; acc[3][2] += av.w*bv.z; acc[3][3] += av.w*bv.w;
        }
        if (more) {                             // stage into the OTHER buffer;
            const int nb = buf ^ 1;             //  one barrier per tile
            As[nb][akq + 0][am] = a_pref.x;
            As[nb][akq + 1][am] = a_pref.y;
            As[nb][akq + 2][am] = a_pref.z;
            As[nb][akq + 3][am] = a_pref.w;
            *(float4*)&Bs[nb][bkk][bnq] = b_pref;
            __syncthreads();
            buf = nb;
        }
    }

    #pragma unroll
    for (int i = 0; i < 4; ++i) {
        const float4 o = make_float4(acc[i][0], acc[i][1], acc[i][2], acc[i][3]);
        *(float4*)&out[(m0 + ty * 4 + i) * H2D + n0 + tx * 4] = o;
    }
}

// ---------------------------------------------------------------------------
// layer2: partials of relu(p1a+p1b+p1c+p1d+b1) @ W2, split-K x8, both branches.
// H recomputed on the fly during A-staging (adds bias, relu). No b2/tanh here.
// H:(512,512), W2:(512,128). Grid (8,2,16): z = branch*8 + ks, K-chunk 64.
// p2[z][512][128]. Same double-buffered template as layer1 (4 tiles, 4
// barriers instead of 8; 6 global streams prefetched ahead of the FMA block).
// ---------------------------------------------------------------------------
__global__ __launch_bounds__(256, 2) void layer2_kernel(
    const float* __restrict__ p1,
    const float* __restrict__ b1_mu, const float* __restrict__ b1_lv,
    const float* __restrict__ w2_mu, const float* __restrict__ w2_lv,
    float* __restrict__ p2)
{
    __shared__ float As[2][16][68];
    __shared__ float Bs[2][16][68];
    const int t = threadIdx.x;

    const int branch = blockIdx.z >> 3;
    const int ks     = blockIdx.z & 7;
    const float* __restrict__ pa = p1 + (size_t)(branch * 4 + 0) * (BSZ * H2D);
    const float* __restrict__ pb = p1 + (size_t)(branch * 4 + 1) * (BSZ * H2D);
    const float* __restrict__ pc = p1 + (size_t)(branch * 4 + 2) * (BSZ * H2D);
    const float* __restrict__ pd = p1 + (size_t)(branch * 4 + 3) * (BSZ * H2D);
    const float* __restrict__ b1 = branch ? b1_lv : b1_mu;
    const float* __restrict__ W  = branch ? w2_lv : w2_mu;
    float* __restrict__ out = p2 + (size_t)blockIdx.z * (BSZ * YD);

    const int m0 = blockIdx.x * 64;
    const int n0 = blockIdx.y * 64;
    const int tx = t & 15;
    const int ty = t >> 4;

    const int am  = t >> 2;
    const int akq = (t & 3) << 2;
    const int bkk = t >> 4;
    const int bnq = (t & 15) << 2;

    const int kbase = ks * 64;
    float acc[4][4] = {};

    float4 pa4 = *(const float4*)&pa[(m0 + am) * H2D + kbase + akq];
    float4 pb4 = *(const float4*)&pb[(m0 + am) * H2D + kbase + akq];
    float4 pc4 = *(const float4*)&pc[(m0 + am) * H2D + kbase + akq];
    float4 pd4 = *(const float4*)&pd[(m0 + am) * H2D + kbase + akq];
    float4 bb4 = *(const float4*)&b1[kbase + akq];
    float4 w4  = *(const float4*)&W[(kbase + bkk) * YD + n0 + bnq];
    As[0][akq + 0][am] = fmaxf(pa4.x + pb4.x + pc4.x + pd4.x + bb4.x, 0.f);
    As[0][akq + 1][am] = fmaxf(pa4.y + pb4.y + pc4.y + pd4.y + bb4.y, 0.f);
    As[0][akq + 2][am] = fmaxf(pa4.z + pb4.z + pc4.z + pd4.z + bb4.z, 0.f);
    As[0][akq + 3][am] = fmaxf(pa4.w + pb4.w + pc4.w + pd4.w + bb4.w, 0.f);
    *(float4*)&Bs[0][bkk][bnq] = w4;
    __syncthreads();

    int buf = 0;
    for (int kt = 0; kt < 64; kt += 16) {
        const bool more = (kt + 16 < 64);
        if (more) {
            const int kn = kbase + kt + 16;
            pa4 = *(const float4*)&pa[(m0 + am) * H2D + kn + akq];
            pb4 = *(const float4*)&pb[(m0 + am) * H2D + kn + akq];
            pc4 = *(const float4*)&pc[(m0 + am) * H2D + kn + akq];
            pd4 = *(const float4*)&pd[(m0 + am) * H2D + kn + akq];
            bb4 = *(const float4*)&b1[kn + akq];
            w4  = *(const float4*)&W[(kn + bkk) * YD + n0 + bnq];
        }
        #pragma unroll
        for (int k = 0; k < 16; ++k) {
            const float4 av = *(const float4*)&As[buf][k][ty * 4];
            const float4 bv = *(const float4*)&Bs[buf][k][tx * 4];
            acc[0][0] += av.x*bv.x; acc[0][1] += av.x*bv.y; acc[0][2] += av.x*bv.z; acc[0][3] += av.x*bv.w;
            acc[1][0] += av.y*bv.x; acc[1][1] += av.y*bv.y; acc[1][2] += av.y*bv.z; acc[1][3] += av.y*bv.w;
            acc[2][0] += av.z*bv.x; acc[2][1] += av.z*bv.y; acc[2][2] += av.z*bv.z; acc[2][3] += av.z*bv.w;
            acc[3][0] += av.w*bv.x; acc[3][1] += av.w*bv.y; acc[3][2] += av.w*bv.z; acc[3][3] += av.w*bv.w;
        }
        if (more) {
            const int nb = buf ^ 1;
            As[nb][akq + 0][am] = fmaxf(pa4.x + pb4.x + pc4.x + pd4.x + bb4.x, 0.f);
            As[nb][akq + 1][am] = fmaxf(pa4.y + pb4.y + pc4.y + pd4.y + bb4.y, 0.f);
            As[nb][akq + 2][am] = fmaxf(pa4.z + pb4.z + pc4.z + pd4.z + bb4.z, 0.f);
            As[nb][akq + 3][am] = fmaxf(pa4.w + pb4.w + pc4.w + pd4.w + bb4.w, 0.f);
            *(float4*)&Bs[nb][bkk][bnq] = w4;
            __syncthreads();
            buf = nb;
        }
    }

    #pragma unroll
    for (int i = 0; i < 4; ++i) {
        const float4 o = make_float4(acc[i][0], acc[i][1], acc[i][2], acc[i][3]);
        *(float4*)&out[(m0 + ty * 4 + i) * YD + n0 + tx * 4] = o;
    }
}

// ---------------------------------------------------------------------------
// reduce (+inline finalize): per element e=(i,d):
//   mu = sum_s p2[s][e] + b2_mu[d];  lv = tanh(sum_s p2[8+s][e] + b2_lv[d])
//   iv = exp(-lv)
//   pos += -0.5*(mu-y)^2*iv - 0.5*lv
//   ap  += iv*(-0.5*Sy2[d] + mu*Sy[d] - 256*mu^2) - 256*lv
// fp32 elementwise, fp64 block reduction + device atomics spread over 16
// accumulator slots (blockIdx&15). Last block (atomic counter) reads the 32
// slots back in parallel and writes the scalar output.
// ---------------------------------------------------------------------------
__global__ __launch_bounds__(256) void reduce_kernel(
    const float* __restrict__ p2, const float* __restrict__ y,
    const float* __restrict__ b2_mu, const float* __restrict__ b2_lv,
    const double* __restrict__ Sy, const double* __restrict__ Sy2,
    double* __restrict__ accum, unsigned int* __restrict__ counter,
    float* __restrict__ outp)
{
    const int NE = BSZ * YD;
    const int e  = blockIdx.x * 256 + threadIdx.x;   // grid 256 covers exactly
    const int d  = e & (YD - 1);

    float mu = b2_mu[d];
    float lp = b2_lv[d];
    #pragma unroll
    for (int s = 0; s < 8; ++s) {
        mu += p2[s * NE + e];
        lp += p2[(8 + s) * NE + e];
    }
    const float lv = tanhf(lp);
    const float iv = expf(-lv);
    const float dm = mu - y[e];

    double pos = -0.5 * (double)dm * (double)dm * (double)iv - 0.5 * (double)lv;
    double ap  = (double)iv * (-0.5 * Sy2[d] + (double)mu * Sy[d]
                               - 256.0 * (double)mu * (double)mu)
               - 256.0 * (double)lv;

    #pragma unroll
    for (int off = 32; off > 0; off >>= 1) {
        pos += __shfl_down(pos, off);
        ap  += __shfl_down(ap, off);
    }
    __shared__ double sp[4];
    __shared__ double sa[4];
    __shared__ double fin[32];
    __shared__ int lastflag;
    const int lane = threadIdx.x & 63;
    const int wv   = threadIdx.x >> 6;
    if (lane == 0) { sp[wv] = pos; sa[wv] = ap; }
    __syncthreads();
    if (threadIdx.x == 0) {
        const int slot = blockIdx.x & 15;
        atomicAdd(&accum[slot],      sp[0] + sp[1] + sp[2] + sp[3]);
        atomicAdd(&accum[16 + slot], sa[0] + sa[1] + sa[2] + sa[3]);
        __threadfence();
        lastflag = (atomicAdd(counter, 1u) == 255u) ? 1 : 0;
    }
    __syncthreads();
    if (lastflag) {                            // last block: finalize
        if (threadIdx.x < 32)                  // coherent parallel read-back
            fin[threadIdx.x] = atomicAdd(&accum[threadIdx.x], 0.0);
        __syncthreads();
        if (threadIdx.x == 0) {
            double P = 0.0, A = 0.0;
            #pragma unroll
            for (int s = 0; s < 16; ++s) { P += fin[s]; A += fin[16 + s]; }
            const double C = log1p(exp(-20.0) / 511.0);
            outp[0] = (float)(P / 512.0 - A / 262144.0 - C);
        }
    }
}

extern "C" void kernel_launch(void* const* d_in, const int* in_sizes, int n_in,
                              void* d_out, int out_size, void* d_ws, size_t ws_size,
                              hipStream_t stream) {
    const float* x     = (const float*)d_in[0];
    const float* y     = (const float*)d_in[1];
    const float* w1_mu = (const float*)d_in[2];
    const float* b1_mu = (const float*)d_in[3];
    const float* w2_mu = (const float*)d_in[4];
    const float* b2_mu = (const float*)d_in[5];
    const float* w1_lv = (const float*)d_in[6];
    const float* b1_lv = (const float*)d_in[7];
    const float* w2_lv = (const float*)d_in[8];
    const float* b2_lv = (const float*)d_in[9];

    char* ws = (char*)d_ws;
    float*  p1 = (float*)(ws);                                     // 8 MB
    float*  p2 = (float*)(ws + (size_t)8 * BSZ * H2D * 4);         // 4 MB
    double* Sy = (double*)(ws + (size_t)8 * BSZ * H2D * 4
                              + (size_t)16 * BSZ * YD * 4);        // 1 KB
    double* Sy2 = Sy + YD;                                         // 1 KB
    double* accum = Sy2 + YD;                                      // 256 B
    unsigned int* counter = (unsigned int*)(accum + 32);           // 4 B

    layer1_kernel<<<dim3(8, 8, 9), 256, 0, stream>>>(
        x, w1_mu, w1_lv, y, p1, Sy, Sy2, accum, counter);
    layer2_kernel<<<dim3(8, 2, 16), 256, 0, stream>>>(
        p1, b1_mu, b1_lv, w2_mu, w2_lv, p2);
    reduce_kernel<<<256, 256, 0, stream>>>(
        p2, y, b2_mu, b2_lv, Sy, Sy2, accum, counter, (float*)d_out);
}